// Round 11
// baseline (356.766 us; speedup 1.0000x reference)
//
#include <hip/hip_runtime.h>

typedef float f4 __attribute__((ext_vector_type(4)));
typedef short s8 __attribute__((ext_vector_type(8)));    // 8 bf16 = 4 VGPRs (MFMA A/B frag)
typedef short s4v __attribute__((ext_vector_type(4)));   // 4 bf16 = 8 B
typedef float f32x4 __attribute__((ext_vector_type(4))); // MFMA C/D frag

__device__ __forceinline__ unsigned short f2bf(float x) {
    unsigned u = __builtin_bit_cast(unsigned, x);
    unsigned r = u + 0x7FFFu + ((u >> 16) & 1u);   // round-to-nearest-even
    return (unsigned short)(r >> 16);
}
__device__ __forceinline__ float bf2f(unsigned short h) {
    unsigned u = ((unsigned)h) << 16;
    return __builtin_bit_cast(float, u);
}

__global__ __launch_bounds__(256) void zero_i32(int* __restrict__ p, int n) {
    int i = blockIdx.x * 256 + threadIdx.x;
    if (i < n) p[i] = 0;
}

__global__ __launch_bounds__(256) void degree_kernel(const int* __restrict__ dst,
                                                     int* __restrict__ deg, int E) {
    int e = blockIdx.x * 256 + threadIdx.x;
    if (e < E) atomicAdd(&deg[dst[e]], 1);
}

// ---- 3-kernel multi-block scan (2048 elems/block in level 1) ----
__global__ __launch_bounds__(256) void scan1(const int* __restrict__ deg,
                                             int* __restrict__ part,
                                             int* __restrict__ bsum, int N) {
    __shared__ int wsum[4];
    const int t = threadIdx.x, lane = t & 63, w = t >> 6;
    const int base = blockIdx.x * 2048 + t * 8;
    int v[8], excl[8];
    int s = 0;
    #pragma unroll
    for (int j = 0; j < 8; ++j) {
        v[j] = (base + j < N) ? deg[base + j] : 0;
        excl[j] = s;
        s += v[j];
    }
    int x = s;
    #pragma unroll
    for (int off = 1; off < 64; off <<= 1) {
        int tt = __shfl_up(x, off, 64);
        if (lane >= off) x += tt;
    }
    if (lane == 63) wsum[w] = x;
    __syncthreads();
    int woff = 0;
    for (int k = 0; k < 4; ++k) if (k < w) woff += wsum[k];
    int ebase = woff + (x - s);
    #pragma unroll
    for (int j = 0; j < 8; ++j)
        if (base + j < N) part[base + j] = ebase + excl[j];
    if (t == 255) bsum[blockIdx.x] = woff + x;
}

__global__ __launch_bounds__(64) void scan2(int* __restrict__ bsum,
                                            int* __restrict__ total_out, int nb) {
    int lane = threadIdx.x;
    int v = (lane < nb) ? bsum[lane] : 0;
    int x = v;
    #pragma unroll
    for (int off = 1; off < 64; off <<= 1) {
        int tt = __shfl_up(x, off, 64);
        if (lane >= off) x += tt;
    }
    if (lane < nb) bsum[lane] = x - v;  // exclusive
    if (lane == 63) total_out[0] = x;
}

__global__ __launch_bounds__(256) void scan3(const int* __restrict__ part,
                                             const int* __restrict__ bsum,
                                             int* __restrict__ row_ptr,
                                             int* __restrict__ cursor, int N) {
    int i = blockIdx.x * 256 + threadIdx.x;
    if (i < N) {
        int val = part[i] + bsum[i >> 11];
        row_ptr[i] = val;
        cursor[i] = val;
    }
}

__global__ __launch_bounds__(256) void scatter_kernel(const int* __restrict__ src,
                                                      const int* __restrict__ dst,
                                                      int* __restrict__ cursor,
                                                      int* __restrict__ ssrc, int E) {
    int e = blockIdx.x * 256 + threadIdx.x;
    if (e < E) {
        int d = dst[e];
        int pos = atomicAdd(&cursor[d], 1);
        ssrc[pos] = src[e];
    }
}

// Split an f32 array into row-major bf16 hi/lo planes. n4 = total elems / 4.
__global__ __launch_bounds__(256) void split_planes(const float* __restrict__ in,
                                                    unsigned short* __restrict__ oh,
                                                    unsigned short* __restrict__ ol,
                                                    int n4) {
    int i = blockIdx.x * 256 + threadIdx.x;
    if (i >= n4) return;
    f4 v = ((const f4*)in)[i];
    s4v hi, lo;
    #pragma unroll
    for (int j = 0; j < 4; ++j) {
        unsigned short h = f2bf(v[j]);
        hi[j] = (short)h;
        lo[j] = (short)f2bf(v[j] - bf2f(h));
    }
    ((s4v*)oh)[i] = hi;
    ((s4v*)ol)[i] = lo;
}

// One 32-lane group per node; lane owns float4 of the 128-wide f32 row. Mean, deg>=1.
// 8 gathered rows in flight (latency-bound fix). Output = bf16 hi/lo planes (row-major).
__global__ __launch_bounds__(256) void agg_kernel(const float* __restrict__ h,
                                                  const int* __restrict__ row_ptr,
                                                  const int* __restrict__ ssrc,
                                                  unsigned short* __restrict__ oh,
                                                  unsigned short* __restrict__ ol,
                                                  int N) {
    int gid = (blockIdx.x * 256 + threadIdx.x) >> 5;
    int lane = threadIdx.x & 31;
    if (gid >= N) return;
    int start = row_ptr[gid];
    int end = row_ptr[gid + 1];
    f4 a0 = {0.f, 0.f, 0.f, 0.f}, a1 = a0, a2 = a0, a3 = a0;
    int e = start;
    for (; e + 8 <= end; e += 8) {
        int s0 = ssrc[e],     s1 = ssrc[e + 1], s2 = ssrc[e + 2], s3 = ssrc[e + 3];
        int s4 = ssrc[e + 4], s5 = ssrc[e + 5], s6 = ssrc[e + 6], s7 = ssrc[e + 7];
        f4 v0 = *(const f4*)(h + (size_t)s0 * 128 + lane * 4);
        f4 v1 = *(const f4*)(h + (size_t)s1 * 128 + lane * 4);
        f4 v2 = *(const f4*)(h + (size_t)s2 * 128 + lane * 4);
        f4 v3 = *(const f4*)(h + (size_t)s3 * 128 + lane * 4);
        f4 v4 = *(const f4*)(h + (size_t)s4 * 128 + lane * 4);
        f4 v5 = *(const f4*)(h + (size_t)s5 * 128 + lane * 4);
        f4 v6 = *(const f4*)(h + (size_t)s6 * 128 + lane * 4);
        f4 v7 = *(const f4*)(h + (size_t)s7 * 128 + lane * 4);
        a0 += v0; a1 += v1; a2 += v2; a3 += v3;
        a0 += v4; a1 += v5; a2 += v6; a3 += v7;
    }
    for (; e + 2 <= end; e += 2) {
        int s0 = ssrc[e], s1 = ssrc[e + 1];
        f4 v0 = *(const f4*)(h + (size_t)s0 * 128 + lane * 4);
        f4 v1 = *(const f4*)(h + (size_t)s1 * 128 + lane * 4);
        a0 += v0; a1 += v1;
    }
    if (e < end) {
        int s0 = ssrc[e];
        a2 += *(const f4*)(h + (size_t)s0 * 128 + lane * 4);
    }
    f4 acc = (a0 + a1) + (a2 + a3);
    float inv = 1.0f / fmaxf((float)(end - start), 1.0f);
    acc *= inv;
    s4v hi, lo;
    #pragma unroll
    for (int j = 0; j < 4; ++j) {
        unsigned short hh = f2bf(acc[j]);
        hi[j] = (short)hh;
        lo[j] = (short)f2bf(acc[j] - bf2f(hh));
    }
    *(s4v*)(oh + (size_t)gid * 128 + lane * 4) = hi;
    *(s4v*)(ol + (size_t)gid * 128 + lane * 4) = lo;
}

// Pack 4 weight matrices (f32 [128][128], row=k, col=n) into bf16 hi/lo MFMA
// B-fragment order: idx t = var*2048 + ks*512 + cf*64 + lane; element j of frag =
// bf16(W[ks*32 + (lane>>4)*8 + j][cf*16 + (lane&15)]). Same k-map as A-frags.
__global__ __launch_bounds__(256) void pack_w(const float* __restrict__ W0,
                                              const float* __restrict__ W1,
                                              const float* __restrict__ W2,
                                              const float* __restrict__ W3,
                                              unsigned short* __restrict__ O0,
                                              unsigned short* __restrict__ O1,
                                              unsigned short* __restrict__ O2,
                                              unsigned short* __restrict__ O3) {
    int t = blockIdx.x * 256 + threadIdx.x;   // 16384 total
    int lane = t & 63;
    int cf = (t >> 6) & 7;
    int ks = (t >> 9) & 3;
    int var = (t >> 11) & 1;
    int mat = t >> 12;
    const float* W = (mat == 0) ? W0 : (mat == 1) ? W1 : (mat == 2) ? W2 : W3;
    unsigned short* O = (mat == 0) ? O0 : (mat == 1) ? O1 : (mat == 2) ? O2 : O3;
    int col = cf * 16 + (lane & 15);
    int k0 = ks * 32 + (lane >> 4) * 8;
    unsigned short v[8];
    #pragma unroll
    for (int j = 0; j < 8; ++j) {
        float x = W[(size_t)(k0 + j) * 128 + col];
        unsigned short hi = f2bf(x);
        v[j] = var ? f2bf(x - bf2f(hi)) : hi;
    }
    *(s8*)(O + (size_t)(t & 4095) * 8) = *(s8*)v;
}

// bf16x3 MFMA GEMM, inputs pre-split to bf16 hi/lo planes (row-major [*][128]).
// out_f32[r][:] = act(A[r]@Ws + An[r]@Wn + bias); optionally also emits out as
// hi/lo planes (DUAL) for the next layer's self-input.
// Staging = pure permute-copy into LDS A-fragment order (XOR-swizzled, same both sides).
// Fragment conventions (cancel-by-construction k-map, measured C/D map):
//   A: lane&15 = row, k = (lane>>4)*8 + j ; B: lane&15 = col, same k-map
//   C/D: col = lane&15, row = (lane>>4)*4 + q
template <int RELU, int DUAL>
__global__ __launch_bounds__(256, 2) void gemm_mfma(const unsigned short* __restrict__ Ah,
                                                    const unsigned short* __restrict__ Al,
                                                    const unsigned short* __restrict__ Anh,
                                                    const unsigned short* __restrict__ Anl,
                                                    const unsigned short* __restrict__ WsPk,
                                                    const unsigned short* __restrict__ WnPk,
                                                    const float* __restrict__ bias,
                                                    float* __restrict__ out,
                                                    unsigned short* __restrict__ out_hi,
                                                    unsigned short* __restrict__ out_lo,
                                                    int N) {
    __shared__ short lds[32768];  // [mat2][var2][ks4][rf4][lane64][8 bf16] = 64 KB
    const int row0 = blockIdx.x * 64;
    const int tid = threadIdx.x;

    const unsigned short* planes[4] = {Ah, Al, Anh, Anl};  // [mat*2+var]

    // ---- stage A/An planes into LDS fragment order (pure copy, 16 B/chunk) ----
    #pragma unroll
    for (int it = 0; it < 16; ++it) {
        int idx = tid + it * 256;            // 0..4095 = [mat2][var2][r64][cg16]
        int mv = idx >> 10;                  // mat*2+var
        int g = idx & 1023;
        int r = g >> 4;
        int cg = g & 15;
        int row = row0 + r;
        if (row >= N) row = N - 1;
        s8 ch = *(const s8*)(planes[mv] + (size_t)row * 128 + cg * 8);
        int u = (mv * 16 + (cg >> 2) * 4 + (r >> 4)) * 64 + (((cg & 3) << 4) | (r & 15));
        u ^= (u >> 4) & 3;
        *(s8*)(lds + (size_t)u * 8) = ch;
    }
    __syncthreads();

    const int l = tid & 63;
    const int w = tid >> 6;
    f32x4 acc[4][2];
    #pragma unroll
    for (int rf = 0; rf < 4; ++rf)
        #pragma unroll
        for (int c = 0; c < 2; ++c) acc[rf][c] = f32x4{0.f, 0.f, 0.f, 0.f};

    const unsigned short* wpk[2] = {WsPk, WnPk};

    #pragma unroll
    for (int ks = 0; ks < 4; ++ks) {
        s8 bfrag[2][2][2];  // [cfi][mat][var]
        #pragma unroll
        for (int cfi = 0; cfi < 2; ++cfi)
            #pragma unroll
            for (int mat = 0; mat < 2; ++mat)
                #pragma unroll
                for (int var = 0; var < 2; ++var) {
                    int cf = w * 2 + cfi;
                    bfrag[cfi][mat][var] = *(const s8*)(wpk[mat] +
                        ((size_t)((var * 4 + ks) * 8 + cf) * 64 + l) * 8);
                }
        s8 afrag[2][2][4];  // [mat][var][rf]
        #pragma unroll
        for (int mat = 0; mat < 2; ++mat)
            #pragma unroll
            for (int var = 0; var < 2; ++var)
                #pragma unroll
                for (int rf = 0; rf < 4; ++rf) {
                    int u = ((mat * 2 + var) * 16 + ks * 4 + rf) * 64 + l;
                    u ^= (u >> 4) & 3;
                    afrag[mat][var][rf] = *(const s8*)(lds + (size_t)u * 8);
                }
        #pragma unroll
        for (int rf = 0; rf < 4; ++rf)
            #pragma unroll
            for (int cfi = 0; cfi < 2; ++cfi)
                #pragma unroll
                for (int mat = 0; mat < 2; ++mat) {
                    acc[rf][cfi] = __builtin_amdgcn_mfma_f32_16x16x32_bf16(
                        afrag[mat][0][rf], bfrag[cfi][mat][0], acc[rf][cfi], 0, 0, 0);
                    acc[rf][cfi] = __builtin_amdgcn_mfma_f32_16x16x32_bf16(
                        afrag[mat][0][rf], bfrag[cfi][mat][1], acc[rf][cfi], 0, 0, 0);
                    acc[rf][cfi] = __builtin_amdgcn_mfma_f32_16x16x32_bf16(
                        afrag[mat][1][rf], bfrag[cfi][mat][0], acc[rf][cfi], 0, 0, 0);
                }
    }

    #pragma unroll
    for (int rf = 0; rf < 4; ++rf)
        #pragma unroll
        for (int cfi = 0; cfi < 2; ++cfi) {
            int col = w * 32 + cfi * 16 + (l & 15);
            float bv = bias[col];
            #pragma unroll
            for (int q = 0; q < 4; ++q) {
                int row = row0 + rf * 16 + (l >> 4) * 4 + q;
                float v = acc[rf][cfi][q] + bv;
                if (RELU) v = fmaxf(v, 0.f);
                if (row < N) {
                    out[(size_t)row * 128 + col] = v;
                    if (DUAL) {
                        unsigned short hh = f2bf(v);
                        out_hi[(size_t)row * 128 + col] = hh;
                        out_lo[(size_t)row * 128 + col] = f2bf(v - bf2f(hh));
                    }
                }
            }
        }
}

extern "C" void kernel_launch(void* const* d_in, const int* in_sizes, int n_in,
                              void* d_out, int out_size, void* d_ws, size_t ws_size,
                              hipStream_t stream) {
    const float* x       = (const float*)d_in[0];
    const int*   src     = (const int*)d_in[1];
    const int*   dst     = (const int*)d_in[2];
    const float* Wself1  = (const float*)d_in[3];
    const float* Wneigh1 = (const float*)d_in[4];
    const float* b1      = (const float*)d_in[5];
    const float* Wself2  = (const float*)d_in[6];
    const float* Wneigh2 = (const float*)d_in[7];
    const float* b2      = (const float*)d_in[8];
    float* out = (float*)d_out;

    const int N = in_sizes[0] / 128;
    const int E = in_sizes[1];

    char* p = (char*)d_ws;
    auto alloc = [&](size_t bytes) {
        char* r = p;
        p += (bytes + 255) & ~(size_t)255;
        return r;
    };
    int*   deg     = (int*)alloc((size_t)N * 4);
    int*   row_ptr = (int*)alloc((size_t)(N + 1) * 4);
    int*   cursor  = (int*)alloc((size_t)N * 4);
    int*   part    = (int*)alloc((size_t)N * 4);
    int*   bsum    = (int*)alloc(64 * 4);
    int*   ssrc    = (int*)alloc((size_t)E * 4);
    float* h1      = (float*)alloc((size_t)N * 128 * 4);
    // bf16 planes: p0 = x planes, later overwritten (disjoint-row-safe) by h1 planes.
    unsigned short* p0h = (unsigned short*)alloc((size_t)N * 128 * 2);
    unsigned short* p0l = (unsigned short*)alloc((size_t)N * 128 * 2);
    unsigned short* p1h = (unsigned short*)alloc((size_t)N * 128 * 2);  // hn planes
    unsigned short* p1l = (unsigned short*)alloc((size_t)N * 128 * 2);
    unsigned short* ws1pk = (unsigned short*)alloc(65536);  // 4096 frags x 16B each
    unsigned short* wn1pk = (unsigned short*)alloc(65536);
    unsigned short* ws2pk = (unsigned short*)alloc(65536);
    unsigned short* wn2pk = (unsigned short*)alloc(65536);
    (void)ws_size;

    const int nb1 = (N + 2047) / 2048;  // 25 (must be <= 64)

    // CSR build
    zero_i32<<<(N + 255) / 256, 256, 0, stream>>>(deg, N);
    degree_kernel<<<(E + 255) / 256, 256, 0, stream>>>(dst, deg, E);
    scan1<<<nb1, 256, 0, stream>>>(deg, part, bsum, N);
    scan2<<<1, 64, 0, stream>>>(bsum, row_ptr + N, nb1);
    scan3<<<(N + 255) / 256, 256, 0, stream>>>(part, bsum, row_ptr, cursor, N);
    scatter_kernel<<<(E + 255) / 256, 256, 0, stream>>>(src, dst, cursor, ssrc, E);

    // Weight split+pack (hi/lo bf16, B-fragment order) + x plane split
    pack_w<<<64, 256, 0, stream>>>(Wself1, Wneigh1, Wself2, Wneigh2,
                                   ws1pk, wn1pk, ws2pk, wn2pk);
    int n4 = N * 32;
    split_planes<<<(n4 + 255) / 256, 256, 0, stream>>>(x, p0h, p0l, n4);

    int agg_blocks = (int)(((size_t)N * 32 + 255) / 256);
    int gemm_blocks = (N + 63) / 64;

    // Layer 1: hn planes from x (f32 gather); h1 = relu(x@Ws1 + hn@Wn1 + b1),
    // emitted as f32 + planes (planes overwrite p0 in place, row-disjoint per block).
    agg_kernel<<<agg_blocks, 256, 0, stream>>>(x, row_ptr, ssrc, p1h, p1l, N);
    gemm_mfma<1, 1><<<gemm_blocks, 256, 0, stream>>>(p0h, p0l, p1h, p1l,
                                                     ws1pk, wn1pk, b1, h1, p0h, p0l, N);

    // Layer 2: hn planes from h1 (f32 gather); out = h1@Ws2 + hn@Wn2 + b2.
    agg_kernel<<<agg_blocks, 256, 0, stream>>>(h1, row_ptr, ssrc, p1h, p1l, N);
    gemm_mfma<0, 0><<<gemm_blocks, 256, 0, stream>>>(p0h, p0l, p1h, p1l,
                                                     ws2pk, wn2pk, b2, out, nullptr, nullptr, N);
}

// Round 12
// 270.144 us; speedup vs baseline: 1.3206x; 1.3206x over previous
//
#include <hip/hip_runtime.h>

typedef float f4 __attribute__((ext_vector_type(4)));
typedef short s8 __attribute__((ext_vector_type(8)));    // 8 bf16 = 4 VGPRs (MFMA A/B frag)
typedef short s4v __attribute__((ext_vector_type(4)));   // 4 bf16 = 8 B
typedef float f32x4 __attribute__((ext_vector_type(4))); // MFMA C/D frag

__device__ __forceinline__ unsigned short f2bf(float x) {
    unsigned u = __builtin_bit_cast(unsigned, x);
    unsigned r = u + 0x7FFFu + ((u >> 16) & 1u);   // round-to-nearest-even
    return (unsigned short)(r >> 16);
}
__device__ __forceinline__ float bf2f(unsigned short h) {
    unsigned u = ((unsigned)h) << 16;
    return __builtin_bit_cast(float, u);
}

__global__ __launch_bounds__(256) void zero_i32(int* __restrict__ p, int n) {
    int i = blockIdx.x * 256 + threadIdx.x;
    if (i < n) p[i] = 0;
}

// Degree count; atomicAdd's return value = this edge's rank within its dst bucket
// (saves the second atomic pass in scatter).
__global__ __launch_bounds__(256) void degree_kernel(const int* __restrict__ dst,
                                                     int* __restrict__ deg,
                                                     int* __restrict__ rank, int E) {
    int e = blockIdx.x * 256 + threadIdx.x;
    if (e < E) rank[e] = atomicAdd(&deg[dst[e]], 1);
}

// ---- 3-kernel multi-block scan (2048 elems/block in level 1) ----
__global__ __launch_bounds__(256) void scan1(const int* __restrict__ deg,
                                             int* __restrict__ part,
                                             int* __restrict__ bsum, int N) {
    __shared__ int wsum[4];
    const int t = threadIdx.x, lane = t & 63, w = t >> 6;
    const int base = blockIdx.x * 2048 + t * 8;
    int v[8], excl[8];
    int s = 0;
    #pragma unroll
    for (int j = 0; j < 8; ++j) {
        v[j] = (base + j < N) ? deg[base + j] : 0;
        excl[j] = s;
        s += v[j];
    }
    int x = s;
    #pragma unroll
    for (int off = 1; off < 64; off <<= 1) {
        int tt = __shfl_up(x, off, 64);
        if (lane >= off) x += tt;
    }
    if (lane == 63) wsum[w] = x;
    __syncthreads();
    int woff = 0;
    for (int k = 0; k < 4; ++k) if (k < w) woff += wsum[k];
    int ebase = woff + (x - s);
    #pragma unroll
    for (int j = 0; j < 8; ++j)
        if (base + j < N) part[base + j] = ebase + excl[j];
    if (t == 255) bsum[blockIdx.x] = woff + x;
}

__global__ __launch_bounds__(64) void scan2(int* __restrict__ bsum,
                                            int* __restrict__ total_out, int nb) {
    int lane = threadIdx.x;
    int v = (lane < nb) ? bsum[lane] : 0;
    int x = v;
    #pragma unroll
    for (int off = 1; off < 64; off <<= 1) {
        int tt = __shfl_up(x, off, 64);
        if (lane >= off) x += tt;
    }
    if (lane < nb) bsum[lane] = x - v;  // exclusive
    if (lane == 63) total_out[0] = x;
}

__global__ __launch_bounds__(256) void scan3(const int* __restrict__ part,
                                             const int* __restrict__ bsum,
                                             int* __restrict__ row_ptr, int N) {
    int i = blockIdx.x * 256 + threadIdx.x;
    if (i < N) row_ptr[i] = part[i] + bsum[i >> 11];
}

// Atomic-free scatter: position = row_ptr[dst] + rank (rank from degree pass).
__global__ __launch_bounds__(256) void scatter_kernel(const int* __restrict__ src,
                                                      const int* __restrict__ dst,
                                                      const int* __restrict__ row_ptr,
                                                      const int* __restrict__ rank,
                                                      int* __restrict__ ssrc, int E) {
    int e = blockIdx.x * 256 + threadIdx.x;
    if (e < E) {
        int d = dst[e];
        ssrc[row_ptr[d] + rank[e]] = src[e];
    }
}

// Split an f32 array into row-major bf16 hi/lo planes. n4 = total elems / 4.
__global__ __launch_bounds__(256) void split_planes(const float* __restrict__ in,
                                                    unsigned short* __restrict__ oh,
                                                    unsigned short* __restrict__ ol,
                                                    int n4) {
    int i = blockIdx.x * 256 + threadIdx.x;
    if (i >= n4) return;
    f4 v = ((const f4*)in)[i];
    s4v hi, lo;
    #pragma unroll
    for (int j = 0; j < 4; ++j) {
        unsigned short h = f2bf(v[j]);
        hi[j] = (short)h;
        lo[j] = (short)f2bf(v[j] - bf2f(h));
    }
    ((s4v*)oh)[i] = hi;
    ((s4v*)ol)[i] = lo;
}

__device__ __forceinline__ f4 ld_bf4(const unsigned short* p) {
    s4v v = *(const s4v*)p;
    f4 r;
    #pragma unroll
    for (int j = 0; j < 4; ++j) r[j] = bf2f((unsigned short)v[j]);
    return r;
}

// One 32-lane group per node; lane owns 4 bf16 (8 B) of the 256 B hi-plane row.
// Gather traffic halved vs f32 (agg is fetch-BW-bound at ~3.7 TB/s, r11 PMC).
// Mean accumulated in f32; output = bf16 hi/lo planes of the mean.
__global__ __launch_bounds__(256) void agg_kernel(const unsigned short* __restrict__ hp,
                                                  const int* __restrict__ row_ptr,
                                                  const int* __restrict__ ssrc,
                                                  unsigned short* __restrict__ oh,
                                                  unsigned short* __restrict__ ol,
                                                  int N) {
    int gid = (blockIdx.x * 256 + threadIdx.x) >> 5;
    int lane = threadIdx.x & 31;
    if (gid >= N) return;
    int start = row_ptr[gid];
    int end = row_ptr[gid + 1];
    f4 a0 = {0.f, 0.f, 0.f, 0.f}, a1 = a0, a2 = a0, a3 = a0;
    int e = start;
    for (; e + 8 <= end; e += 8) {
        int s0 = ssrc[e],     s1 = ssrc[e + 1], s2 = ssrc[e + 2], s3 = ssrc[e + 3];
        int s4 = ssrc[e + 4], s5 = ssrc[e + 5], s6 = ssrc[e + 6], s7 = ssrc[e + 7];
        f4 v0 = ld_bf4(hp + (size_t)s0 * 128 + lane * 4);
        f4 v1 = ld_bf4(hp + (size_t)s1 * 128 + lane * 4);
        f4 v2 = ld_bf4(hp + (size_t)s2 * 128 + lane * 4);
        f4 v3 = ld_bf4(hp + (size_t)s3 * 128 + lane * 4);
        f4 v4 = ld_bf4(hp + (size_t)s4 * 128 + lane * 4);
        f4 v5 = ld_bf4(hp + (size_t)s5 * 128 + lane * 4);
        f4 v6 = ld_bf4(hp + (size_t)s6 * 128 + lane * 4);
        f4 v7 = ld_bf4(hp + (size_t)s7 * 128 + lane * 4);
        a0 += v0; a1 += v1; a2 += v2; a3 += v3;
        a0 += v4; a1 += v5; a2 += v6; a3 += v7;
    }
    for (; e + 2 <= end; e += 2) {
        int s0 = ssrc[e], s1 = ssrc[e + 1];
        a0 += ld_bf4(hp + (size_t)s0 * 128 + lane * 4);
        a1 += ld_bf4(hp + (size_t)s1 * 128 + lane * 4);
    }
    if (e < end) {
        int s0 = ssrc[e];
        a2 += ld_bf4(hp + (size_t)s0 * 128 + lane * 4);
    }
    f4 acc = (a0 + a1) + (a2 + a3);
    float inv = 1.0f / fmaxf((float)(end - start), 1.0f);
    acc *= inv;
    s4v hi, lo;
    #pragma unroll
    for (int j = 0; j < 4; ++j) {
        unsigned short hh = f2bf(acc[j]);
        hi[j] = (short)hh;
        lo[j] = (short)f2bf(acc[j] - bf2f(hh));
    }
    *(s4v*)(oh + (size_t)gid * 128 + lane * 4) = hi;
    *(s4v*)(ol + (size_t)gid * 128 + lane * 4) = lo;
}

// Pack 4 weight matrices (f32 [128][128], row=k, col=n) into bf16 hi/lo MFMA
// B-fragment order: idx t = var*2048 + ks*512 + cf*64 + lane; element j of frag =
// bf16(W[ks*32 + (lane>>4)*8 + j][cf*16 + (lane&15)]). Same k-map as A-frags.
__global__ __launch_bounds__(256) void pack_w(const float* __restrict__ W0,
                                              const float* __restrict__ W1,
                                              const float* __restrict__ W2,
                                              const float* __restrict__ W3,
                                              unsigned short* __restrict__ O0,
                                              unsigned short* __restrict__ O1,
                                              unsigned short* __restrict__ O2,
                                              unsigned short* __restrict__ O3) {
    int t = blockIdx.x * 256 + threadIdx.x;   // 16384 total
    int lane = t & 63;
    int cf = (t >> 6) & 7;
    int ks = (t >> 9) & 3;
    int var = (t >> 11) & 1;
    int mat = t >> 12;
    const float* W = (mat == 0) ? W0 : (mat == 1) ? W1 : (mat == 2) ? W2 : W3;
    unsigned short* O = (mat == 0) ? O0 : (mat == 1) ? O1 : (mat == 2) ? O2 : O3;
    int col = cf * 16 + (lane & 15);
    int k0 = ks * 32 + (lane >> 4) * 8;
    unsigned short v[8];
    #pragma unroll
    for (int j = 0; j < 8; ++j) {
        float x = W[(size_t)(k0 + j) * 128 + col];
        unsigned short hi = f2bf(x);
        v[j] = var ? f2bf(x - bf2f(hi)) : hi;
    }
    *(s8*)(O + (size_t)(t & 4095) * 8) = *(s8*)v;
}

// bf16x3 MFMA GEMM, inputs pre-split to bf16 hi/lo planes (row-major [*][128]).
// out_f32[r][:] = act(A[r]@Ws + An[r]@Wn + bias); optionally also emits out as
// hi/lo planes (DUAL) for the next layer's self-input + neighbor gather table.
// Staging = pure permute-copy into LDS A-fragment order (XOR-swizzled, same both sides).
// Fragment conventions (cancel-by-construction k-map, measured C/D map):
//   A: lane&15 = row, k = (lane>>4)*8 + j ; B: lane&15 = col, same k-map
//   C/D: col = lane&15, row = (lane>>4)*4 + q
template <int RELU, int DUAL>
__global__ __launch_bounds__(256, 2) void gemm_mfma(const unsigned short* __restrict__ Ah,
                                                    const unsigned short* __restrict__ Al,
                                                    const unsigned short* __restrict__ Anh,
                                                    const unsigned short* __restrict__ Anl,
                                                    const unsigned short* __restrict__ WsPk,
                                                    const unsigned short* __restrict__ WnPk,
                                                    const float* __restrict__ bias,
                                                    float* __restrict__ out,
                                                    unsigned short* __restrict__ out_hi,
                                                    unsigned short* __restrict__ out_lo,
                                                    int N) {
    __shared__ short lds[32768];  // [mat2][var2][ks4][rf4][lane64][8 bf16] = 64 KB
    const int row0 = blockIdx.x * 64;
    const int tid = threadIdx.x;

    const unsigned short* planes[4] = {Ah, Al, Anh, Anl};  // [mat*2+var]

    // ---- stage A/An planes into LDS fragment order (pure copy, 16 B/chunk) ----
    #pragma unroll
    for (int it = 0; it < 16; ++it) {
        int idx = tid + it * 256;            // 0..4095 = [mat2][var2][r64][cg16]
        int mv = idx >> 10;                  // mat*2+var
        int g = idx & 1023;
        int r = g >> 4;
        int cg = g & 15;
        int row = row0 + r;
        if (row >= N) row = N - 1;
        s8 ch = *(const s8*)(planes[mv] + (size_t)row * 128 + cg * 8);
        int u = (mv * 16 + (cg >> 2) * 4 + (r >> 4)) * 64 + (((cg & 3) << 4) | (r & 15));
        u ^= (u >> 4) & 3;
        *(s8*)(lds + (size_t)u * 8) = ch;
    }
    __syncthreads();

    const int l = tid & 63;
    const int w = tid >> 6;
    f32x4 acc[4][2];
    #pragma unroll
    for (int rf = 0; rf < 4; ++rf)
        #pragma unroll
        for (int c = 0; c < 2; ++c) acc[rf][c] = f32x4{0.f, 0.f, 0.f, 0.f};

    const unsigned short* wpk[2] = {WsPk, WnPk};

    #pragma unroll
    for (int ks = 0; ks < 4; ++ks) {
        s8 bfrag[2][2][2];  // [cfi][mat][var]
        #pragma unroll
        for (int cfi = 0; cfi < 2; ++cfi)
            #pragma unroll
            for (int mat = 0; mat < 2; ++mat)
                #pragma unroll
                for (int var = 0; var < 2; ++var) {
                    int cf = w * 2 + cfi;
                    bfrag[cfi][mat][var] = *(const s8*)(wpk[mat] +
                        ((size_t)((var * 4 + ks) * 8 + cf) * 64 + l) * 8);
                }
        s8 afrag[2][2][4];  // [mat][var][rf]
        #pragma unroll
        for (int mat = 0; mat < 2; ++mat)
            #pragma unroll
            for (int var = 0; var < 2; ++var)
                #pragma unroll
                for (int rf = 0; rf < 4; ++rf) {
                    int u = ((mat * 2 + var) * 16 + ks * 4 + rf) * 64 + l;
                    u ^= (u >> 4) & 3;
                    afrag[mat][var][rf] = *(const s8*)(lds + (size_t)u * 8);
                }
        #pragma unroll
        for (int rf = 0; rf < 4; ++rf)
            #pragma unroll
            for (int cfi = 0; cfi < 2; ++cfi)
                #pragma unroll
                for (int mat = 0; mat < 2; ++mat) {
                    acc[rf][cfi] = __builtin_amdgcn_mfma_f32_16x16x32_bf16(
                        afrag[mat][0][rf], bfrag[cfi][mat][0], acc[rf][cfi], 0, 0, 0);
                    acc[rf][cfi] = __builtin_amdgcn_mfma_f32_16x16x32_bf16(
                        afrag[mat][0][rf], bfrag[cfi][mat][1], acc[rf][cfi], 0, 0, 0);
                    acc[rf][cfi] = __builtin_amdgcn_mfma_f32_16x16x32_bf16(
                        afrag[mat][1][rf], bfrag[cfi][mat][0], acc[rf][cfi], 0, 0, 0);
                }
    }

    #pragma unroll
    for (int rf = 0; rf < 4; ++rf)
        #pragma unroll
        for (int cfi = 0; cfi < 2; ++cfi) {
            int col = w * 32 + cfi * 16 + (l & 15);
            float bv = bias[col];
            #pragma unroll
            for (int q = 0; q < 4; ++q) {
                int row = row0 + rf * 16 + (l >> 4) * 4 + q;
                float v = acc[rf][cfi][q] + bv;
                if (RELU) v = fmaxf(v, 0.f);
                if (row < N) {
                    out[(size_t)row * 128 + col] = v;
                    if (DUAL) {
                        unsigned short hh = f2bf(v);
                        out_hi[(size_t)row * 128 + col] = hh;
                        out_lo[(size_t)row * 128 + col] = f2bf(v - bf2f(hh));
                    }
                }
            }
        }
}

extern "C" void kernel_launch(void* const* d_in, const int* in_sizes, int n_in,
                              void* d_out, int out_size, void* d_ws, size_t ws_size,
                              hipStream_t stream) {
    const float* x       = (const float*)d_in[0];
    const int*   src     = (const int*)d_in[1];
    const int*   dst     = (const int*)d_in[2];
    const float* Wself1  = (const float*)d_in[3];
    const float* Wneigh1 = (const float*)d_in[4];
    const float* b1      = (const float*)d_in[5];
    const float* Wself2  = (const float*)d_in[6];
    const float* Wneigh2 = (const float*)d_in[7];
    const float* b2      = (const float*)d_in[8];
    float* out = (float*)d_out;

    const int N = in_sizes[0] / 128;
    const int E = in_sizes[1];

    char* p = (char*)d_ws;
    auto alloc = [&](size_t bytes) {
        char* r = p;
        p += (bytes + 255) & ~(size_t)255;
        return r;
    };
    int*   deg     = (int*)alloc((size_t)N * 4);
    int*   row_ptr = (int*)alloc((size_t)(N + 1) * 4);
    int*   part    = (int*)alloc((size_t)N * 4);
    int*   bsum    = (int*)alloc(64 * 4);
    int*   rank    = (int*)alloc((size_t)E * 4);
    int*   ssrc    = (int*)alloc((size_t)E * 4);
    float* h1      = (float*)alloc((size_t)N * 128 * 4);
    // bf16 planes: p0 = x planes, later overwritten (disjoint-row-safe) by h1 planes.
    unsigned short* p0h = (unsigned short*)alloc((size_t)N * 128 * 2);
    unsigned short* p0l = (unsigned short*)alloc((size_t)N * 128 * 2);
    unsigned short* p1h = (unsigned short*)alloc((size_t)N * 128 * 2);  // hn planes
    unsigned short* p1l = (unsigned short*)alloc((size_t)N * 128 * 2);
    unsigned short* ws1pk = (unsigned short*)alloc(65536);  // 4096 frags x 16B each
    unsigned short* wn1pk = (unsigned short*)alloc(65536);
    unsigned short* ws2pk = (unsigned short*)alloc(65536);
    unsigned short* wn2pk = (unsigned short*)alloc(65536);
    (void)ws_size;

    const int nb1 = (N + 2047) / 2048;  // 25 (must be <= 64)

    // CSR build (single atomic pass: degree emits per-edge rank)
    zero_i32<<<(N + 255) / 256, 256, 0, stream>>>(deg, N);
    degree_kernel<<<(E + 255) / 256, 256, 0, stream>>>(dst, deg, rank, E);
    scan1<<<nb1, 256, 0, stream>>>(deg, part, bsum, N);
    scan2<<<1, 64, 0, stream>>>(bsum, row_ptr + N, nb1);
    scan3<<<(N + 255) / 256, 256, 0, stream>>>(part, bsum, row_ptr, N);
    scatter_kernel<<<(E + 255) / 256, 256, 0, stream>>>(src, dst, row_ptr, rank, ssrc, E);

    // Weight split+pack (hi/lo bf16, B-fragment order) + x plane split
    pack_w<<<64, 256, 0, stream>>>(Wself1, Wneigh1, Wself2, Wneigh2,
                                   ws1pk, wn1pk, ws2pk, wn2pk);
    int n4 = N * 32;
    split_planes<<<(n4 + 255) / 256, 256, 0, stream>>>(x, p0h, p0l, n4);

    int agg_blocks = (int)(((size_t)N * 32 + 255) / 256);
    int gemm_blocks = (N + 63) / 64;

    // Layer 1: hn planes from x-hi gather (bf16); h1 = relu(x@Ws1 + hn@Wn1 + b1),
    // emitted as f32 + planes (planes overwrite p0 in place, row-disjoint per block).
    agg_kernel<<<agg_blocks, 256, 0, stream>>>(p0h, row_ptr, ssrc, p1h, p1l, N);
    gemm_mfma<1, 1><<<gemm_blocks, 256, 0, stream>>>(p0h, p0l, p1h, p1l,
                                                     ws1pk, wn1pk, b1, h1, p0h, p0l, N);

    // Layer 2: hn planes from h1-hi gather (bf16); out = h1@Ws2 + hn@Wn2 + b2.
    agg_kernel<<<agg_blocks, 256, 0, stream>>>(p0h, row_ptr, ssrc, p1h, p1l, N);
    gemm_mfma<0, 0><<<gemm_blocks, 256, 0, stream>>>(p0h, p0l, p1h, p1l,
                                                     ws2pk, wn2pk, b2, out, nullptr, nullptr, N);
}